// Round 1
// baseline (518.944 us; speedup 1.0000x reference)
//
#include <hip/hip_runtime.h>

// Problem: B=16, C=64 (in=out), H=W=128, 3x3 conv of box-summed input.
// out = conv3x3_zeropad(s, W_eff), s = 3x3 reflect-pad box sum of x,
// W_eff = W with center tap reduced by THETA * sum(W over 3x3).

#define THETA 0.7f
#define NB 16
#define NC 64
#define NH 128
#define NW 128

// ---------------------------------------------------------------------------
// Kernel 1: W_eff transform. W: OIHW [64][64][3][3].
// Output layout Wt[k][o], k = i*9 + ky*3 + kx  (64 o contiguous per k).
// ---------------------------------------------------------------------------
__global__ void weff_kernel(const float* __restrict__ W, float* __restrict__ Wt) {
    int t = blockIdx.x * blockDim.x + threadIdx.x;
    if (t >= NC * NC) return;
    int o = t & 63;
    int i = t >> 6;
    const float* w = W + ((size_t)o * NC + i) * 9;
    float v[9];
    float sum = 0.f;
#pragma unroll
    for (int k = 0; k < 9; k++) { v[k] = w[k]; sum += v[k]; }
#pragma unroll
    for (int k = 0; k < 9; k++) {
        float val = v[k] - ((k == 4) ? THETA * sum : 0.f);
        Wt[(i * 9 + k) * NC + o] = val;
    }
}

// ---------------------------------------------------------------------------
// Kernel 2: 3x3 box sum with reflect padding.
// Block: 256 threads, 8 output rows of one (b,c) plane. Grid: 16*64*16.
// ---------------------------------------------------------------------------
__global__ __launch_bounds__(256) void boxsum_kernel(const float* __restrict__ x,
                                                     float* __restrict__ s) {
    __shared__ float rows[10 * NW];
    __shared__ float vs[8 * NW];
    int bid = blockIdx.x;
    int bc = bid >> 4;
    int h0 = (bid & 15) * 8;
    const float* xp = x + (size_t)bc * (NH * NW);
    float* sp = s + (size_t)bc * (NH * NW);
    int tid = threadIdx.x;

    // stage 10 raw rows (h0-1 .. h0+8), reflected at image edges
    for (int idx = tid; idx < 10 * NW; idx += 256) {
        int r = idx >> 7;
        int w = idx & 127;
        int hr = h0 - 1 + r;
        if (hr < 0) hr = 1;          // reflect(-1) = 1
        if (hr > NH - 1) hr = NH - 2; // reflect(H) = H-2
        rows[idx] = xp[hr * NW + w];
    }
    __syncthreads();

    // vertical 3-sums for the 8 output rows
    for (int idx = tid; idx < 8 * NW; idx += 256) {
        int r = idx >> 7;
        int w = idx & 127;
        vs[idx] = rows[r * NW + w] + rows[(r + 1) * NW + w] + rows[(r + 2) * NW + w];
    }
    __syncthreads();

    // horizontal 3-sums with reflect in w
    for (int idx = tid; idx < 8 * NW; idx += 256) {
        int r = idx >> 7;
        int w = idx & 127;
        int wm = (w == 0) ? 1 : w - 1;
        int wp = (w == NW - 1) ? NW - 2 : w + 1;
        sp[(h0 + r) * NW + w] = vs[r * NW + wm] + vs[idx] + vs[r * NW + wp];
    }
}

// ---------------------------------------------------------------------------
// Kernel 3: direct 3x3 conv, 64 -> 64 channels, zero padding.
// Block: 256 threads. Each block: one (b, h), w-tile of 64, all 64 out chans.
// LDS: s tile [64 ch][3 rows][68 w] (w padded to 68 for 16B-aligned reads).
// Thread: 2 consecutive o x 8 consecutive w = 16 accumulators.
// Grid: 16 * 128 * 2 = 4096 blocks.
// ---------------------------------------------------------------------------
#define SROW 68          // padded LDS row width (66 used)
__global__ __launch_bounds__(256) void conv_kernel(const float* __restrict__ s,
                                                   const float* __restrict__ Wt,
                                                   float* __restrict__ out) {
    __shared__ float sS[NC * 3 * SROW];   // 52224 B

    int bid = blockIdx.x;
    int b = bid >> 8;
    int rem = bid & 255;
    int h = rem >> 1;
    int w0 = (rem & 1) * 64;
    int tid = threadIdx.x;

    // ---- stage s tile: rows h-1..h+1 (zero-pad), cols w0-1..w0+66 (zero-pad)
    const float* sb = s + (size_t)b * (NC * NH * NW);
    for (int idx = tid; idx < NC * 3 * SROW; idx += 256) {
        int i = idx / (3 * SROW);
        int r2 = idx - i * (3 * SROW);
        int ky = r2 / SROW;
        int wl = r2 - ky * SROW;
        int r = h - 1 + ky;
        int gw = w0 - 1 + wl;
        float v = 0.f;
        if ((unsigned)r < (unsigned)NH && (unsigned)gw < (unsigned)NW)
            v = sb[(i * NH + r) * NW + gw];
        sS[idx] = v;
    }
    __syncthreads();

    int o_base = (tid >> 3) * 2;       // 0,2,..,62
    int w_base = (tid & 7) * 8;        // 0,8,..,56

    float acc[2][8];
#pragma unroll
    for (int a = 0; a < 2; a++)
#pragma unroll
        for (int j = 0; j < 8; j++) acc[a][j] = 0.f;

    for (int i = 0; i < NC; i++) {
#pragma unroll
        for (int ky = 0; ky < 3; ky++) {
            const float* srow = &sS[(i * 3 + ky) * SROW + w_base];
            float sv[10];
#pragma unroll
            for (int j = 0; j < 10; j++) sv[j] = srow[j];
            const float* wp = Wt + (i * 9 + ky * 3) * NC + o_base;
            float2 wv0 = *(const float2*)(wp);
            float2 wv1 = *(const float2*)(wp + NC);
            float2 wv2 = *(const float2*)(wp + 2 * NC);
#pragma unroll
            for (int j = 0; j < 8; j++) {
                acc[0][j] += wv0.x * sv[j] + wv1.x * sv[j + 1] + wv2.x * sv[j + 2];
                acc[1][j] += wv0.y * sv[j] + wv1.y * sv[j + 1] + wv2.y * sv[j + 2];
            }
        }
    }

    float* ob = out + (((size_t)b * NC + o_base) * NH + h) * NW + w0 + w_base;
#pragma unroll
    for (int a = 0; a < 2; a++) {
        float4* dst = (float4*)(ob + (size_t)a * NH * NW);
        dst[0] = make_float4(acc[a][0], acc[a][1], acc[a][2], acc[a][3]);
        dst[1] = make_float4(acc[a][4], acc[a][5], acc[a][6], acc[a][7]);
    }
}

// ---------------------------------------------------------------------------
extern "C" void kernel_launch(void* const* d_in, const int* in_sizes, int n_in,
                              void* d_out, int out_size, void* d_ws, size_t ws_size,
                              hipStream_t stream) {
    const float* x = (const float*)d_in[0];   // [16][64][128][128]
    const float* W = (const float*)d_in[1];   // [64][64][3][3]
    float* outp = (float*)d_out;              // [16][64][128][128]

    // workspace layout: Wt (576*64 fp32 = 147456 B) | s (64 MiB)
    float* Wt = (float*)d_ws;
    float* s = (float*)((char*)d_ws + 576 * 64 * sizeof(float));

    weff_kernel<<<16, 256, 0, stream>>>(W, Wt);
    boxsum_kernel<<<NB * NC * (NH / 8), 256, 0, stream>>>(x, s);
    conv_kernel<<<NB * NH * 2, 256, 0, stream>>>(s, Wt, outp);
}

// Round 2
// 228.545 us; speedup vs baseline: 2.2706x; 2.2706x over previous
//
#include <hip/hip_runtime.h>
#include <stdint.h>

// out = conv3x3_zeropad(s, W_eff), s = 3x3 reflect-pad box sum of x (B=16,C=64,H=W=128)
// W_eff[o][i][ky][kx] = W[..] - (tap==center)*THETA*sum_tap W[o][i][:]
// Implemented as: vsum (NCHW fp32, tmp=d_out) -> hsum+transpose (NHWC bf16)
// -> implicit-GEMM bf16 MFMA conv (9 shifted 64x64 GEMMs, fp32 accum).

#define THETA 0.7f

typedef __attribute__((ext_vector_type(8))) short bf16x8;
typedef __attribute__((ext_vector_type(4))) float f32x4;

__device__ inline unsigned short f2bf(float f) {
    unsigned u = __float_as_uint(f);
    u = (u + 0x7FFFu + ((u >> 16) & 1u)) >> 16;   // round-to-nearest-even
    return (unsigned short)u;
}

__device__ inline void async16(const void* g, void* l) {
    __builtin_amdgcn_global_load_lds(
        (const __attribute__((address_space(1))) unsigned int*)g,
        (__attribute__((address_space(3))) unsigned int*)l, 16, 0, 0);
}

// ---------------------------------------------------------------------------
// Kernel 1: W_eff -> Wt[tap][o][i] bf16 (tap = ky*3+kx)
// ---------------------------------------------------------------------------
__global__ void weff_kernel(const float* __restrict__ W, unsigned short* __restrict__ Wt) {
    int t = blockIdx.x * blockDim.x + threadIdx.x;  // 4096 = 64 o x 64 i
    if (t >= 64 * 64) return;
    int i = t & 63;
    int o = t >> 6;
    const float* w = W + ((size_t)o * 64 + i) * 9;
    float v[9];
    float sum = 0.f;
#pragma unroll
    for (int k = 0; k < 9; k++) { v[k] = w[k]; sum += v[k]; }
#pragma unroll
    for (int k = 0; k < 9; k++) {
        float val = v[k] - ((k == 4) ? THETA * sum : 0.f);
        Wt[((size_t)k * 64 + o) * 64 + i] = f2bf(val);
    }
}

// ---------------------------------------------------------------------------
// Kernel 2: vertical 3-sum, reflect pad. NCHW fp32 -> NCHW fp32 (tmp).
// Block: 8 output rows of one (b,c) plane. Grid: 16*64*16.
// ---------------------------------------------------------------------------
__global__ __launch_bounds__(256) void vsum_kernel(const float* __restrict__ x,
                                                   float* __restrict__ tmp) {
    __shared__ float rows[10 * 128];
    int bid = blockIdx.x;
    int bc = bid >> 4;
    int h0 = (bid & 15) * 8;
    const float* xp = x + (size_t)bc * 16384;
    float* tp = tmp + (size_t)bc * 16384;
    int tid = threadIdx.x;
    for (int idx = tid; idx < 10 * 128; idx += 256) {
        int r = idx >> 7, w = idx & 127;
        int hr = h0 - 1 + r;
        if (hr < 0) hr = 1;
        if (hr > 127) hr = 126;
        rows[idx] = xp[hr * 128 + w];
    }
    __syncthreads();
    for (int idx = tid; idx < 8 * 128; idx += 256) {
        int r = idx >> 7, w = idx & 127;
        tp[(h0 + r) * 128 + w] = rows[r * 128 + w] + rows[(r + 1) * 128 + w] + rows[(r + 2) * 128 + w];
    }
}

// ---------------------------------------------------------------------------
// Kernel 3: horizontal 3-sum (reflect) + NCHW->NHWC transpose + bf16.
// Block: one (b,h). Grid: 16*128.
// ---------------------------------------------------------------------------
__global__ __launch_bounds__(256) void hsum_kernel(const float* __restrict__ tmp,
                                                   unsigned short* __restrict__ s) {
    __shared__ float vt[128 * 67];   // [w][c], stride 67 to break conflicts
    int bid = blockIdx.x;
    int b = bid >> 7, h = bid & 127;
    const float* tp = tmp + ((size_t)b * 64) * 16384 + (size_t)h * 128;
    int tid = threadIdx.x;
    // stage 64c x 128w (float4 over w), store transposed [w][c]
#pragma unroll
    for (int it = 0; it < 8; it++) {
        int idx4 = it * 256 + tid;        // 0..2047
        int c = idx4 >> 5;
        int w4 = (idx4 & 31) * 4;
        float4 v = *(const float4*)(tp + (size_t)c * 16384 + w4);
        vt[(w4 + 0) * 67 + c] = v.x;
        vt[(w4 + 1) * 67 + c] = v.y;
        vt[(w4 + 2) * 67 + c] = v.z;
        vt[(w4 + 3) * 67 + c] = v.w;
    }
    __syncthreads();
    unsigned short* sp = s + ((size_t)b * 128 + h) * 8192;   // 128 w * 64 c
    int c2 = (tid & 31) * 2;
    int wq = tid >> 5;
#pragma unroll
    for (int it = 0; it < 16; it++) {
        int w = it * 8 + wq;
        int wm = (w == 0) ? 1 : w - 1;
        int wp = (w == 127) ? 126 : w + 1;
        float v0 = vt[wm * 67 + c2] + vt[w * 67 + c2] + vt[wp * 67 + c2];
        float v1 = vt[wm * 67 + c2 + 1] + vt[w * 67 + c2 + 1] + vt[wp * 67 + c2 + 1];
        ushort2 o2 = make_ushort2(f2bf(v0), f2bf(v1));
        *(ushort2*)(sp + w * 64 + c2) = o2;
    }
}

// ---------------------------------------------------------------------------
// Kernel 4: implicit-GEMM conv. Block = one (b,h) output row, 256 thr (4 waves).
// Wave: 32 pixels (2 n-frags), all 64 o (4 m-frags). K = 9 taps x 64 c.
// LDS: 3 rows x 130 pixel-slots x 64c bf16 = 49920 B, XOR-swizzled 16B chunks.
// Chunk u (8 ch) of pixel-slot p stored at position g = u ^ (p&7).
// ---------------------------------------------------------------------------
__global__ __launch_bounds__(256, 3) void conv_kernel(const unsigned short* __restrict__ s,
                                                      const unsigned short* __restrict__ Wt,
                                                      float* __restrict__ out) {
    __shared__ __align__(16) unsigned short sS[3 * 130 * 64];

    int bid = blockIdx.x;
    int b = bid >> 7;
    int h = bid & 127;
    int tid = threadIdx.x;
    int lane = tid & 63;
    int wv = tid >> 6;
    int n = lane & 15;
    int q = lane >> 4;
    int wb = wv * 32;            // wave's pixel base

    int4 z4 = make_int4(0, 0, 0, 0);
    // zero out-of-image rows (block-uniform, edge blocks only)
    if (h == 0) {
        for (int idx = tid; idx < 1040; idx += 256)
            *(int4*)((char*)sS + idx * 16) = z4;
    }
    if (h == 127) {
        for (int idx = tid; idx < 1040; idx += 256)
            *(int4*)((char*)sS + 2 * 16640 + idx * 16) = z4;
    }
    // zero halo pixel-slots 0 and 129 of each row
    if (tid < 48) {
        int row = tid >> 4, k = tid & 15;
        int slot = (k < 8) ? 0 : 129, ch = k & 7;
        *(int4*)((char*)sS + ((size_t)(row * 130 + slot)) * 128 + ch * 16) = z4;
    }

    // stage 3 rows x 128 pixels x 128B via global_load_lds (swizzle in gaddr)
    const char* sbase = (const char*)s + ((size_t)b * 128) * 16384;
    int u_l = (lane & 7) ^ (((lane >> 3) + 1) & 7);
#pragma unroll
    for (int i2 = 0; i2 < 12; i2++) {
        int t2 = wv * 12 + i2;          // 0..47
        int row = t2 >> 4;              // 0..2
        int j = t2 & 15;                // 0..15 (8 pixels each)
        int hg = h - 1 + row;
        if (hg >= 0 && hg < 128) {
            int pg = j * 8 + (lane >> 3);
            const char* ga = sbase + (size_t)hg * 16384 + pg * 128 + u_l * 16;
            unsigned short* la = sS + ((size_t)(row * 130 + 1 + j * 8)) * 64 + lane * 8;
            async16(ga, la);
        }
    }
    __syncthreads();

    const unsigned short* Wl = Wt + n * 64 + q * 8;   // lane's A base
    f32x4 acc[4][2];
#pragma unroll
    for (int mf = 0; mf < 4; mf++)
#pragma unroll
        for (int nf = 0; nf < 2; nf++) acc[mf][nf] = (f32x4){0.f, 0.f, 0.f, 0.f};

#pragma unroll
    for (int ky = 0; ky < 3; ky++) {
#pragma unroll
        for (int kx = 0; kx < 3; kx++) {
            int p0 = wb + n + kx;                 // pixel-slot for nf=0
            int pg7 = (n + kx) & 7;
#pragma unroll
            for (int ic = 0; ic < 2; ic++) {
                int g = (ic * 4 + q) ^ pg7;
                bf16x8 bfr0 = *(const bf16x8*)(sS + ((size_t)(ky * 130 + p0)) * 64 + g * 8);
                bf16x8 bfr1 = *(const bf16x8*)(sS + ((size_t)(ky * 130 + p0 + 16)) * 64 + g * 8);
                const unsigned short* wp = Wl + ((ky * 3 + kx) * 4096 + ic * 32);
                bf16x8 a0 = *(const bf16x8*)(wp);
                bf16x8 a1 = *(const bf16x8*)(wp + 1024);
                bf16x8 a2 = *(const bf16x8*)(wp + 2048);
                bf16x8 a3 = *(const bf16x8*)(wp + 3072);
                acc[0][0] = __builtin_amdgcn_mfma_f32_16x16x32_bf16(a0, bfr0, acc[0][0], 0, 0, 0);
                acc[0][1] = __builtin_amdgcn_mfma_f32_16x16x32_bf16(a0, bfr1, acc[0][1], 0, 0, 0);
                acc[1][0] = __builtin_amdgcn_mfma_f32_16x16x32_bf16(a1, bfr0, acc[1][0], 0, 0, 0);
                acc[1][1] = __builtin_amdgcn_mfma_f32_16x16x32_bf16(a1, bfr1, acc[1][1], 0, 0, 0);
                acc[2][0] = __builtin_amdgcn_mfma_f32_16x16x32_bf16(a2, bfr0, acc[2][0], 0, 0, 0);
                acc[2][1] = __builtin_amdgcn_mfma_f32_16x16x32_bf16(a2, bfr1, acc[2][1], 0, 0, 0);
                acc[3][0] = __builtin_amdgcn_mfma_f32_16x16x32_bf16(a3, bfr0, acc[3][0], 0, 0, 0);
                acc[3][1] = __builtin_amdgcn_mfma_f32_16x16x32_bf16(a3, bfr1, acc[3][1], 0, 0, 0);
            }
        }
    }

    // epilogue: C/D layout col=lane&15 (pixel), row=q*4+reg (o)
    float* ob = out + ((size_t)b * 64) * 16384 + (size_t)h * 128;
#pragma unroll
    for (int mf = 0; mf < 4; mf++) {
#pragma unroll
        for (int nf = 0; nf < 2; nf++) {
            int w = wb + nf * 16 + n;
#pragma unroll
            for (int r = 0; r < 4; r++) {
                int o = mf * 16 + q * 4 + r;
                ob[(size_t)o * 16384 + w] = acc[mf][nf][r];
            }
        }
    }
}

// ---------------------------------------------------------------------------
extern "C" void kernel_launch(void* const* d_in, const int* in_sizes, int n_in,
                              void* d_out, int out_size, void* d_ws, size_t ws_size,
                              hipStream_t stream) {
    const float* x = (const float*)d_in[0];   // [16][64][128][128]
    const float* W = (const float*)d_in[1];   // [64][64][3][3]
    float* outp = (float*)d_out;

    // ws: Wt bf16 (73728 B) | s bf16 NHWC (33554432 B).  tmp = d_out (fp32 NCHW).
    unsigned short* Wt = (unsigned short*)d_ws;
    unsigned short* s = (unsigned short*)((char*)d_ws + 73728);
    float* tmp = outp;

    weff_kernel<<<16, 256, 0, stream>>>(W, Wt);
    vsum_kernel<<<16 * 64 * 16, 256, 0, stream>>>(x, tmp);
    hsum_kernel<<<16 * 128, 256, 0, stream>>>(tmp, s);
    conv_kernel<<<16 * 128, 256, 0, stream>>>(s, Wt, outp);
}

// Round 4
// 182.629 us; speedup vs baseline: 2.8415x; 1.2514x over previous
//
#include <hip/hip_runtime.h>
#include <stdint.h>

// out = conv3x3_zeropad(s, W_eff), s = 3x3 reflect-pad box sum of x (B=16,C=64,H=W=128)
// Pipeline: vsum (fp32 NCHW -> bf16 NCHW, tmp in d_out) -> hsumT (bf16 NCHW ->
// bf16 NHWC s in ws) -> implicit-GEMM bf16 MFMA conv (4-row blocks, fp32 accum).
// R4 fix: all global_load_lds issues are FULL-WAVE (wave-uniform predicates only);
// halo columns staged via plain loads + ds_write (per-lane divergence safe there).

#define THETA 0.7f

typedef __attribute__((ext_vector_type(8))) short bf16x8;
typedef __attribute__((ext_vector_type(4))) float f32x4;

__device__ inline unsigned short f2bf(float f) {
    unsigned u = __float_as_uint(f);
    u = (u + 0x7FFFu + ((u >> 16) & 1u)) >> 16;   // RNE
    return (unsigned short)u;
}
__device__ inline float bf2f(unsigned short u) {
    return __uint_as_float((unsigned)u << 16);
}
__device__ inline void async16(const void* g, void* l) {
    __builtin_amdgcn_global_load_lds(
        (const __attribute__((address_space(1))) unsigned int*)g,
        (__attribute__((address_space(3))) unsigned int*)l, 16, 0, 0);
}

// ---------------------------------------------------------------------------
// Kernel 1: W_eff -> Wt[tap][o][i] bf16 (tap = ky*3+kx)
// ---------------------------------------------------------------------------
__global__ void weff_kernel(const float* __restrict__ W, unsigned short* __restrict__ Wt) {
    int t = blockIdx.x * blockDim.x + threadIdx.x;
    if (t >= 64 * 64) return;
    int i = t & 63;
    int o = t >> 6;
    const float* w = W + ((size_t)o * 64 + i) * 9;
    float v[9];
    float sum = 0.f;
#pragma unroll
    for (int k = 0; k < 9; k++) { v[k] = w[k]; sum += v[k]; }
#pragma unroll
    for (int k = 0; k < 9; k++) {
        float val = v[k] - ((k == 4) ? THETA * sum : 0.f);
        Wt[((size_t)k * 64 + o) * 64 + i] = f2bf(val);
    }
}

// ---------------------------------------------------------------------------
// Kernel 2: vertical 3-sum, reflect pad. fp32 NCHW -> bf16 NCHW (tmp).
// Rolling-register column pass, no LDS. Thread = (plane, strip of 32 h, w4).
// ---------------------------------------------------------------------------
__global__ __launch_bounds__(256) void vsum_kernel(const float* __restrict__ x,
                                                   unsigned short* __restrict__ tmp) {
    int t = blockIdx.x * 256 + threadIdx.x;
    int w4 = (t & 31) * 4;
    int strip = (t >> 5) & 3;
    int plane = t >> 7;                  // b*64 + c
    const float* xp = x + (size_t)plane * 16384 + w4;
    unsigned short* tp = tmp + (size_t)plane * 16384 + w4;
    int h0 = strip * 32;

    int hm = (h0 - 1 < 0) ? 1 : h0 - 1;
    float4 a = *(const float4*)(xp + hm * 128);
    float4 b = *(const float4*)(xp + h0 * 128);
#pragma unroll 4
    for (int i = 0; i < 32; i++) {
        int hn = h0 + 1 + i;
        if (hn > 127) hn = 126;
        float4 c = *(const float4*)(xp + hn * 128);
        float sx = a.x + b.x + c.x;
        float sy = a.y + b.y + c.y;
        float sz = a.z + b.z + c.z;
        float sw = a.w + b.w + c.w;
        ushort4 o = make_ushort4(f2bf(sx), f2bf(sy), f2bf(sz), f2bf(sw));
        *(ushort4*)(tp + (h0 + i) * 128) = o;
        a = b; b = c;
    }
}

// ---------------------------------------------------------------------------
// Kernel 3: horizontal 3-sum (reflect) + NCHW->NHWC transpose.
// bf16 NCHW tmp -> bf16 NHWC s. Block = one (b,h). Grid 2048.
// ---------------------------------------------------------------------------
__global__ __launch_bounds__(256) void hsumT_kernel(const unsigned short* __restrict__ tmp,
                                                    unsigned short* __restrict__ s) {
    __shared__ float vt[128 * 67];       // [w][c], stride 67: transpose buffer
    int bid = blockIdx.x;
    int b = bid >> 7, h = bid & 127;
    int tid = threadIdx.x;
    const unsigned short* tb = tmp + (size_t)b * 64 * 16384 + (size_t)h * 128;

#pragma unroll
    for (int it = 0; it < 4; it++) {
        int id = it * 256 + tid;
        int c = id >> 4;
        int w8 = (id & 15) * 8;
        bf16x8 v = *(const bf16x8*)(tb + (size_t)c * 16384 + w8);
#pragma unroll
        for (int k = 0; k < 8; k++)
            vt[(w8 + k) * 67 + c] = bf2f((unsigned short)v[k]);
    }
    __syncthreads();

    int w = tid >> 1, c0 = (tid & 1) * 32;
    int wm = (w == 0) ? 1 : w - 1;
    int wp = (w == 127) ? 126 : w + 1;
    const float* r0 = vt + wm * 67 + c0;
    const float* r1 = vt + w * 67 + c0;
    const float* r2 = vt + wp * 67 + c0;
    unsigned short* sp = s + (size_t)bid * 8192 + (size_t)w * 64 + c0;
#pragma unroll
    for (int k = 0; k < 4; k++) {
        bf16x8 o;
#pragma unroll
        for (int j = 0; j < 8; j++) {
            float v = r0[k * 8 + j] + r1[k * 8 + j] + r2[k * 8 + j];
            o[j] = (short)f2bf(v);
        }
        *(bf16x8*)(sp + k * 8) = o;
    }
}

// ---------------------------------------------------------------------------
// Kernel 4: implicit-GEMM conv. Block = (b, 4 h-rows, 64-px w-tile), 4 waves.
// Wave = 1 output row: 64 px (4 nf) x 64 o (4 mf), acc[4][4].
// LDS: 6 rows x 66 slots x 64c bf16 = 50688 B, 16B chunks XOR-swizzled:
// chunk u of slot p lives at LDS position g = u ^ (p&7).
// Staging: interior 64 px/row via full-wave global_load_lds (512 chunks/row =
// 2 iters of 256 thr -> row predicate iteration-uniform); halo slots 0/65 via
// plain loads + ds_write_b128. Grid 16*32*2 = 1024.
// ---------------------------------------------------------------------------
__global__ __launch_bounds__(256, 3) void conv_kernel(const unsigned short* __restrict__ s,
                                                      const unsigned short* __restrict__ Wt,
                                                      float* __restrict__ out) {
    __shared__ __align__(16) unsigned short sS[6 * 66 * 64];   // 50688 B

    int bid = blockIdx.x;
    int b = bid >> 6;
    int h0 = ((bid >> 1) & 31) * 4;
    int w0 = (bid & 1) * 64;
    int tid = threadIdx.x;
    int lane = tid & 63;
    int wv = tid >> 6;
    int n = lane & 15;
    int q = lane >> 4;

    const char* sb = (const char*)s + ((size_t)b * 128) * 16384;  // bytes: b plane

    int4 z = make_int4(0, 0, 0, 0);
    // zero whole out-of-image rows (block-uniform)
    if (h0 == 0)
        for (int i = tid; i < 528; i += 256) *(int4*)((char*)sS + (size_t)i * 16) = z;
    if (h0 == 124)
        for (int i = tid; i < 528; i += 256) *(int4*)((char*)sS + (size_t)(5 * 528 + i) * 16) = z;

    // halo pixel columns: slots 0 and 65 of each row (96 chunks), plain path
    if (tid < 96) {
        int r = tid >> 4;            // 0..5
        int side = (tid >> 3) & 1;   // 0: slot 0, 1: slot 65
        int g = tid & 7;
        int slot = side ? 65 : 0;
        int hg = h0 - 1 + r;
        int wg = w0 - 1 + slot;
        int4 v = z;
        if ((unsigned)hg < 128u && (unsigned)wg < 128u) {
            int u = g ^ (slot & 7);
            v = *(const int4*)(sb + (size_t)hg * 16384 + (size_t)wg * 128 + u * 16);
        }
        *(int4*)((char*)sS + (size_t)(r * 528 + slot * 8 + g) * 16) = v;
    }

    // interior: rows 0..5, pixels w0..w0+63 (512 chunks/row), full-wave async
#pragma unroll
    for (int it = 0; it < 12; it++) {
        int row = it >> 1;
        int hg = h0 - 1 + row;
        if (hg < 0 || hg > 127) continue;          // iteration-uniform
        int rem = (it & 1) * 256 + tid;            // 0..511 within the row
        int slot = 1 + (rem >> 3);
        int g = rem & 7;
        int wg = w0 + (rem >> 3);
        int u = g ^ (slot & 7);
        async16(sb + (size_t)hg * 16384 + (size_t)wg * 128 + u * 16,
                (char*)sS + (size_t)(row * 528 + 8 + rem) * 16);
    }
    __syncthreads();

    const unsigned short* Wl = Wt + n * 64 + q * 8;
    // LDS base per (kx, ic); ky adds +4224 shorts, nf adds +1024
    const unsigned short* bbase[3][2];
#pragma unroll
    for (int kx = 0; kx < 3; kx++)
#pragma unroll
        for (int ic = 0; ic < 2; ic++) {
            int g = (ic * 4 + q) ^ ((n + kx) & 7);
            bbase[kx][ic] = sS + ((size_t)(wv * 66 + n + kx)) * 64 + g * 8;
        }

    f32x4 acc[4][4];
#pragma unroll
    for (int mf = 0; mf < 4; mf++)
#pragma unroll
        for (int nf = 0; nf < 4; nf++) acc[mf][nf] = (f32x4){0.f, 0.f, 0.f, 0.f};

#pragma unroll
    for (int ky = 0; ky < 3; ky++) {
#pragma unroll
        for (int kx = 0; kx < 3; kx++) {
#pragma unroll
            for (int ic = 0; ic < 2; ic++) {
                const unsigned short* wp = Wl + ((ky * 3 + kx) * 4096 + ic * 32);
                bf16x8 a0 = *(const bf16x8*)(wp);
                bf16x8 a1 = *(const bf16x8*)(wp + 1024);
                bf16x8 a2 = *(const bf16x8*)(wp + 2048);
                bf16x8 a3 = *(const bf16x8*)(wp + 3072);
                const unsigned short* bp = bbase[kx][ic] + ky * 4224;
                bf16x8 b0 = *(const bf16x8*)(bp);
                bf16x8 b1 = *(const bf16x8*)(bp + 1024);
                bf16x8 b2 = *(const bf16x8*)(bp + 2048);
                bf16x8 b3 = *(const bf16x8*)(bp + 3072);
                acc[0][0] = __builtin_amdgcn_mfma_f32_16x16x32_bf16(a0, b0, acc[0][0], 0, 0, 0);
                acc[0][1] = __builtin_amdgcn_mfma_f32_16x16x32_bf16(a0, b1, acc[0][1], 0, 0, 0);
                acc[0][2] = __builtin_amdgcn_mfma_f32_16x16x32_bf16(a0, b2, acc[0][2], 0, 0, 0);
                acc[0][3] = __builtin_amdgcn_mfma_f32_16x16x32_bf16(a0, b3, acc[0][3], 0, 0, 0);
                acc[1][0] = __builtin_amdgcn_mfma_f32_16x16x32_bf16(a1, b0, acc[1][0], 0, 0, 0);
                acc[1][1] = __builtin_amdgcn_mfma_f32_16x16x32_bf16(a1, b1, acc[1][1], 0, 0, 0);
                acc[1][2] = __builtin_amdgcn_mfma_f32_16x16x32_bf16(a1, b2, acc[1][2], 0, 0, 0);
                acc[1][3] = __builtin_amdgcn_mfma_f32_16x16x32_bf16(a1, b3, acc[1][3], 0, 0, 0);
                acc[2][0] = __builtin_amdgcn_mfma_f32_16x16x32_bf16(a2, b0, acc[2][0], 0, 0, 0);
                acc[2][1] = __builtin_amdgcn_mfma_f32_16x16x32_bf16(a2, b1, acc[2][1], 0, 0, 0);
                acc[2][2] = __builtin_amdgcn_mfma_f32_16x16x32_bf16(a2, b2, acc[2][2], 0, 0, 0);
                acc[2][3] = __builtin_amdgcn_mfma_f32_16x16x32_bf16(a2, b3, acc[2][3], 0, 0, 0);
                acc[3][0] = __builtin_amdgcn_mfma_f32_16x16x32_bf16(a3, b0, acc[3][0], 0, 0, 0);
                acc[3][1] = __builtin_amdgcn_mfma_f32_16x16x32_bf16(a3, b1, acc[3][1], 0, 0, 0);
                acc[3][2] = __builtin_amdgcn_mfma_f32_16x16x32_bf16(a3, b2, acc[3][2], 0, 0, 0);
                acc[3][3] = __builtin_amdgcn_mfma_f32_16x16x32_bf16(a3, b3, acc[3][3], 0, 0, 0);
            }
        }
    }

    // epilogue: C/D layout col(lane&15)=pixel, row(q*4+r)=o
    float* ob = out + ((size_t)b * 64) * 16384 + (size_t)(h0 + wv) * 128 + w0 + n;
#pragma unroll
    for (int mf = 0; mf < 4; mf++)
#pragma unroll
        for (int nf = 0; nf < 4; nf++)
#pragma unroll
            for (int r = 0; r < 4; r++) {
                int o = mf * 16 + q * 4 + r;
                ob[(size_t)o * 16384 + nf * 16] = acc[mf][nf][r];
            }
}

// ---------------------------------------------------------------------------
extern "C" void kernel_launch(void* const* d_in, const int* in_sizes, int n_in,
                              void* d_out, int out_size, void* d_ws, size_t ws_size,
                              hipStream_t stream) {
    const float* x = (const float*)d_in[0];   // [16][64][128][128] fp32
    const float* W = (const float*)d_in[1];   // [64][64][3][3] fp32
    float* outp = (float*)d_out;

    // ws: Wt bf16 (73728 B) | s bf16 NHWC (33554432 B)
    // tmp (bf16 NCHW, 32 MB) lives in d_out; consumed by hsumT before conv writes.
    unsigned short* Wt = (unsigned short*)d_ws;
    unsigned short* s = (unsigned short*)((char*)d_ws + 73728);
    unsigned short* tmp = (unsigned short*)d_out;

    weff_kernel<<<16, 256, 0, stream>>>(W, Wt);
    vsum_kernel<<<512, 256, 0, stream>>>(x, tmp);
    hsumT_kernel<<<2048, 256, 0, stream>>>(tmp, s);
    conv_kernel<<<1024, 256, 0, stream>>>(s, Wt, outp);
}

// Round 5
// 142.186 us; speedup vs baseline: 3.6497x; 1.2844x over previous
//
#include <hip/hip_runtime.h>
#include <stdint.h>

// out = conv3x3_zeropad(s, W_eff), s = 3x3 reflect-pad box sum of x (B=16,C=64,H=W=128)
// R5: boxsumT (fp32 NCHW -> bf16 NHWC, fused vert+horiz+transpose) ->
// implicit-GEMM conv with mfma_32x32x16_bf16, tap-major A-prefetch from
// lane-contiguous Wt2, XOR-swizzled LDS staging (from R4, verified).

#define THETA 0.7f

typedef __attribute__((ext_vector_type(8))) short bf16x8;
typedef __attribute__((ext_vector_type(16))) float f32x16;

__device__ inline unsigned short f2bf(float f) {
    unsigned u = __float_as_uint(f);
    u = (u + 0x7FFFu + ((u >> 16) & 1u)) >> 16;   // RNE
    return (unsigned short)u;
}
__device__ inline void async16(const void* g, void* l) {
    __builtin_amdgcn_global_load_lds(
        (const __attribute__((address_space(1))) unsigned int*)g,
        (__attribute__((address_space(3))) unsigned int*)l, 16, 0, 0);
}

// ---------------------------------------------------------------------------
// Kernel 1: W_eff -> Wt2 bf16, lane-contiguous MFMA-A layout:
// Wt2[(((tap*4+ic)*2+mf)*64 + lane)*8 + j] = W_eff[o][ch][tap]
//   o = mf*32 + (lane&31), ch = ic*16 + (lane>>5)*8 + j
// Total 9*4*2*64*8 = 36864 shorts = 73728 B.
// ---------------------------------------------------------------------------
__global__ void weff_kernel(const float* __restrict__ W, unsigned short* __restrict__ Wt2) {
    int t = blockIdx.x * blockDim.x + threadIdx.x;   // 512 threads
    if (t >= 512) return;
    int o = t >> 3;
    int ch8 = t & 7;
    int c0 = ch8 * 8;
    int ic = ch8 >> 1;
    int mf = o >> 5;
    int lane = (o & 31) | ((ch8 & 1) << 5);

    float v[8][9];
    float tsum[8];
#pragma unroll
    for (int j = 0; j < 8; j++) {
        const float* w = W + ((size_t)o * 64 + c0 + j) * 9;
        float sum = 0.f;
#pragma unroll
        for (int k = 0; k < 9; k++) { v[j][k] = w[k]; sum += v[j][k]; }
        tsum[j] = sum;
    }
#pragma unroll
    for (int tap = 0; tap < 9; tap++) {
        unsigned short* dst = Wt2 + (((size_t)(tap * 4 + ic) * 2 + mf) * 64 + lane) * 8;
#pragma unroll
        for (int j = 0; j < 8; j++) {
            float val = v[j][tap] - ((tap == 4) ? THETA * tsum[j] : 0.f);
            dst[j] = f2bf(val);
        }
    }
}

// ---------------------------------------------------------------------------
// Kernel 2: fused box-sum + transpose. x fp32 NCHW -> s bf16 NHWC.
// Block = (b, 8-h strip), 512 thr: w4 = tid&31 (float4 along w), cg = tid>>5
// (4 channels each). Rolling vertical float4 sums; horizontal via shfl within
// 32-lane w-groups (reflect at edges); per-row LDS transpose (stride 72
// shorts -> 16B-aligned flush); coalesced full-line NHWC stores.
// Grid 16*16 = 256.
// ---------------------------------------------------------------------------
__global__ __launch_bounds__(512) void boxsumT_kernel(const float* __restrict__ x,
                                                      unsigned short* __restrict__ s) {
    __shared__ unsigned short tb[128 * 72];   // 18432 B
    int bid = blockIdx.x;
    int b = bid >> 4;
    int h0 = (bid & 15) * 8;
    int tid = threadIdx.x;
    int w4 = tid & 31;
    int cg = tid >> 5;          // 0..15
    int c0 = cg * 4;
    const float* xp = x + ((size_t)(b * 64 + c0)) * 16384 + w4 * 4;

    float4 A[4], B[4], C[4];
    int hm = (h0 == 0) ? 1 : h0 - 1;
#pragma unroll
    for (int cc = 0; cc < 4; cc++) {
        A[cc] = *(const float4*)(xp + (size_t)cc * 16384 + hm * 128);
        B[cc] = *(const float4*)(xp + (size_t)cc * 16384 + h0 * 128);
        C[cc] = *(const float4*)(xp + (size_t)cc * 16384 + (h0 + 1) * 128);
    }

#pragma unroll
    for (int r = 0; r < 8; r++) {
        // prefetch next C (issued before compute so latency overlaps)
        float4 Cn[4];
        if (r < 7) {
            int hn = h0 + 2 + r;
            if (hn > 127) hn = 126;
#pragma unroll
            for (int cc = 0; cc < 4; cc++)
                Cn[cc] = *(const float4*)(xp + (size_t)cc * 16384 + hn * 128);
        }

        unsigned short res[4][4];   // [cc][k]
#pragma unroll
        for (int cc = 0; cc < 4; cc++) {
            float4 vs;
            vs.x = A[cc].x + B[cc].x + C[cc].x;
            vs.y = A[cc].y + B[cc].y + C[cc].y;
            vs.z = A[cc].z + B[cc].z + C[cc].z;
            vs.w = A[cc].w + B[cc].w + C[cc].w;
            float L = __shfl_up(vs.w, 1, 32);
            float R = __shfl_down(vs.x, 1, 32);
            float sx = (w4 == 0) ? vs.x + 2.f * vs.y : L + vs.x + vs.y;
            float sy = vs.x + vs.y + vs.z;
            float sz = vs.y + vs.z + vs.w;
            float sw = (w4 == 31) ? 2.f * vs.z + vs.w : vs.z + vs.w + R;
            res[cc][0] = f2bf(sx);
            res[cc][1] = f2bf(sy);
            res[cc][2] = f2bf(sz);
            res[cc][3] = f2bf(sw);
        }
        // write transpose buffer: tb[w][c], stride 72
#pragma unroll
        for (int k = 0; k < 4; k++) {
            ushort4 o4 = make_ushort4(res[0][k], res[1][k], res[2][k], res[3][k]);
            *(ushort4*)(tb + (size_t)(w4 * 4 + k) * 72 + c0) = o4;
        }
#pragma unroll
        for (int cc = 0; cc < 4; cc++) { A[cc] = B[cc]; B[cc] = C[cc]; C[cc] = Cn[cc]; }
        __syncthreads();

        // flush row h0+r: 1024 chunks of 16 B, full-line NHWC stores
        unsigned short* sp = s + (((size_t)b * 128 + (h0 + r)) * 128) * 64;
#pragma unroll
        for (int f = 0; f < 2; f++) {
            int id = f * 512 + tid;
            int w = id >> 3, c8 = id & 7;
            bf16x8 v = *(const bf16x8*)(tb + (size_t)w * 72 + c8 * 8);
            *(bf16x8*)(sp + (size_t)w * 64 + c8 * 8) = v;
        }
        __syncthreads();
    }
}

// ---------------------------------------------------------------------------
// Kernel 3: implicit-GEMM conv, mfma_f32_32x32x16_bf16.
// Block = (b, 4 h-rows, 64-px w-tile), 4 waves; wave = 1 row x 64 px x 64 o
// (mf=2 x nf=2, acc[2][2] of f32x16). LDS staging identical to R4 (verified):
// 6 rows x 66 slots x 64c bf16, 16B chunks XOR-swizzled g = u ^ (slot&7).
// A from global Wt2 (lane-contiguous), tap-major prefetch. Grid 1024.
// ---------------------------------------------------------------------------
__global__ __launch_bounds__(256, 2) void conv_kernel(const unsigned short* __restrict__ s,
                                                      const unsigned short* __restrict__ Wt2,
                                                      float* __restrict__ out) {
    __shared__ __align__(16) unsigned short sS[6 * 66 * 64];   // 50688 B

    int bid = blockIdx.x;
    int b = bid >> 6;
    int h0 = ((bid >> 1) & 31) * 4;
    int w0 = (bid & 1) * 64;
    int tid = threadIdx.x;
    int lane = tid & 63;
    int wv = tid >> 6;
    int n32 = lane & 31;
    int q2 = lane >> 5;

    const char* sb = (const char*)s + ((size_t)b * 128) * 16384;

    int4 z = make_int4(0, 0, 0, 0);
    if (h0 == 0)
        for (int i = tid; i < 528; i += 256) *(int4*)((char*)sS + (size_t)i * 16) = z;
    if (h0 == 124)
        for (int i = tid; i < 528; i += 256) *(int4*)((char*)sS + (size_t)(5 * 528 + i) * 16) = z;

    // halo slots 0 and 65 (plain loads; per-lane divergence safe here)
    if (tid < 96) {
        int r = tid >> 4;
        int side = (tid >> 3) & 1;
        int g = tid & 7;
        int slot = side ? 65 : 0;
        int hg = h0 - 1 + r;
        int wg = w0 - 1 + slot;
        int4 v = z;
        if ((unsigned)hg < 128u && (unsigned)wg < 128u) {
            int u = g ^ (slot & 7);
            v = *(const int4*)(sb + (size_t)hg * 16384 + (size_t)wg * 128 + u * 16);
        }
        *(int4*)((char*)sS + (size_t)(r * 528 + slot * 8 + g) * 16) = v;
    }

    // interior: full-wave async, iteration-uniform row predicate
#pragma unroll
    for (int it = 0; it < 12; it++) {
        int row = it >> 1;
        int hg = h0 - 1 + row;
        if (hg < 0 || hg > 127) continue;
        int rem = (it & 1) * 256 + tid;
        int slot = 1 + (rem >> 3);
        int g = rem & 7;
        int wg = w0 + (rem >> 3);
        int u = g ^ (slot & 7);
        async16(sb + (size_t)hg * 16384 + (size_t)wg * 128 + u * 16,
                (char*)sS + (size_t)(row * 528 + 8 + rem) * 16);
    }
    __syncthreads();

    // B LDS offsets (shorts) per (kx, ic); add (wv+ky)*4224 + nf*2048
    int p0[3][4];
#pragma unroll
    for (int kx = 0; kx < 3; kx++)
#pragma unroll
        for (int ic = 0; ic < 4; ic++) {
            int slot = n32 + kx;
            int g = (ic * 2 + q2) ^ (slot & 7);
            p0[kx][ic] = slot * 64 + g * 8;
        }

    f32x16 acc[2][2];
#pragma unroll
    for (int mf = 0; mf < 2; mf++)
#pragma unroll
        for (int nf = 0; nf < 2; nf++)
#pragma unroll
            for (int r = 0; r < 16; r++) acc[mf][nf][r] = 0.f;

    // A-frags for tap 0
    bf16x8 Af[8], An[8];
#pragma unroll
    for (int ic = 0; ic < 4; ic++)
#pragma unroll
        for (int mf = 0; mf < 2; mf++)
            Af[ic * 2 + mf] = *(const bf16x8*)(Wt2 + (((size_t)(0 * 4 + ic) * 2 + mf) * 64 + lane) * 8);

#pragma unroll
    for (int tap = 0; tap < 9; tap++) {
        int ky = tap / 3, kx = tap % 3;
        if (tap < 8) {
#pragma unroll
            for (int ic = 0; ic < 4; ic++)
#pragma unroll
                for (int mf = 0; mf < 2; mf++)
                    An[ic * 2 + mf] = *(const bf16x8*)(Wt2 + (((size_t)((tap + 1) * 4 + ic) * 2 + mf) * 64 + lane) * 8);
        }
#pragma unroll
        for (int ic = 0; ic < 4; ic++) {
            const unsigned short* bp = sS + (size_t)(wv + ky) * 4224 + p0[kx][ic];
            bf16x8 b0 = *(const bf16x8*)(bp);
            bf16x8 b1 = *(const bf16x8*)(bp + 2048);
            acc[0][0] = __builtin_amdgcn_mfma_f32_32x32x16_bf16(Af[ic * 2 + 0], b0, acc[0][0], 0, 0, 0);
            acc[0][1] = __builtin_amdgcn_mfma_f32_32x32x16_bf16(Af[ic * 2 + 0], b1, acc[0][1], 0, 0, 0);
            acc[1][0] = __builtin_amdgcn_mfma_f32_32x32x16_bf16(Af[ic * 2 + 1], b0, acc[1][0], 0, 0, 0);
            acc[1][1] = __builtin_amdgcn_mfma_f32_32x32x16_bf16(Af[ic * 2 + 1], b1, acc[1][1], 0, 0, 0);
        }
        if (tap < 8) {
#pragma unroll
            for (int k = 0; k < 8; k++) Af[k] = An[k];
        }
    }

    // epilogue: 32x32 C/D layout col=lane&31 (pixel), row=(r&3)+8*(r>>2)+4*q2 (o)
    float* ob = out + ((size_t)b * 64) * 16384 + (size_t)(h0 + wv) * 128 + w0;
#pragma unroll
    for (int mf = 0; mf < 2; mf++)
#pragma unroll
        for (int nf = 0; nf < 2; nf++)
#pragma unroll
            for (int r = 0; r < 16; r++) {
                int o = mf * 32 + (r & 3) + 8 * (r >> 2) + 4 * q2;
                ob[(size_t)o * 16384 + nf * 32 + n32] = acc[mf][nf][r];
            }
}

// ---------------------------------------------------------------------------
extern "C" void kernel_launch(void* const* d_in, const int* in_sizes, int n_in,
                              void* d_out, int out_size, void* d_ws, size_t ws_size,
                              hipStream_t stream) {
    const float* x = (const float*)d_in[0];   // [16][64][128][128] fp32
    const float* W = (const float*)d_in[1];   // [64][64][3][3] fp32
    float* outp = (float*)d_out;

    // ws: Wt2 bf16 (73728 B) | s bf16 NHWC (33554432 B)
    unsigned short* Wt2 = (unsigned short*)d_ws;
    unsigned short* s = (unsigned short*)((char*)d_ws + 73728);

    weff_kernel<<<2, 256, 0, stream>>>(W, Wt2);
    boxsumT_kernel<<<256, 512, 0, stream>>>(x, s);
    conv_kernel<<<1024, 256, 0, stream>>>(s, Wt2, outp);
}